// Round 8
// baseline (148.580 us; speedup 1.0000x reference)
//
#include <hip/hip_runtime.h>

// Kernel 1: per-block partial sums of squared differences.
//
// R8: global_load_lds staging, now with EXPLICIT synchronization (R7 read
// the LDS destinations with no vmcnt wait — the compiler does NOT track
// the global_load_lds -> ds_read dependency; absmax 3.6e10).
//
// Mechanism under test: reads return directly to LDS, bypassing the
// VGPR-writeback/wave-wakeup path shared by all seven prior variants
// (all pinned at 3.15-3.44 TB/s effective read, vs 6.5 TB/s on the
// write-only fill path).
//
// Schedule per wave (no cross-wave sharing -> ZERO barriers in the loop):
//   stage(k+1) -> slot (k+1)%3        (2x global_load_lds, 1 KB each)
//   s_waitcnt vmcnt(2)                (chunk k's 2 loads retired; k+1 in flight)
//   sched_barrier(0)                  (ds_reads may not hoist above the wait)
//   consume slot k%3                  (ds_read_b128 + FP)
// Triple buffer: the slot stage(k+1) overwrites was consumed at k-2, two
// iterations + two waits earlier -> WAR closed architecturally.
// Last iteration waits vmcnt(0). Never drains to 0 mid-loop.
//
// LDS: [3 bufs][2 streams][4 waves][64 lanes] float4 = 24 KB/block;
// 4 blocks/CU (launch_bounds 256,4) -> 96 KB <= 160 KB.
// Per-thread accumulation order identical to R5/R6 -> bit-exact.
__global__ __launch_bounds__(256, 4) void ssd_partials(const float4* __restrict__ p,
                                                       const float4* __restrict__ t,
                                                       float* __restrict__ ws) {
    const int tid  = threadIdx.x;
    const int lane = tid & 63;
    const int wave = tid >> 6;
    const long long stride = 2047LL * 256;               // float4s per chunk
    const long long i0 = (long long)blockIdx.x * 256 + tid;

    __shared__ float4 st[3][2][4][64];                   // 24 KB

    typedef const __attribute__((address_space(1))) float gfloat;
    typedef __attribute__((address_space(3))) float lfloat;

    const float4* gp = p + i0;                           // per-lane global src
    const float4* gt = t + i0;

    // Prologue: chunk 0 -> slot 0. LDS dest is wave-uniform; HW adds lane*16.
    __builtin_amdgcn_global_load_lds((gfloat*)gp, (lfloat*)&st[0][0][wave][0], 16, 0, 0);
    __builtin_amdgcn_global_load_lds((gfloat*)gt, (lfloat*)&st[0][1][wave][0], 16, 0, 0);

    float acc0 = 0.f, acc1 = 0.f, acc2 = 0.f, acc3 = 0.f;
    #pragma unroll
    for (int k = 0; k < 8; ++k) {
        if (k < 7) {
            __builtin_amdgcn_global_load_lds((gfloat*)(gp + (k + 1) * stride),
                                             (lfloat*)&st[(k + 1) % 3][0][wave][0], 16, 0, 0);
            __builtin_amdgcn_global_load_lds((gfloat*)(gt + (k + 1) * stride),
                                             (lfloat*)&st[(k + 1) % 3][1][wave][0], 16, 0, 0);
            // vmcnt(2): chunk k's two loads retired, chunk k+1's stay in flight.
            __builtin_amdgcn_s_waitcnt(0xF72);
        } else {
            // Last chunk: nothing in flight behind it -> vmcnt(0).
            __builtin_amdgcn_s_waitcnt(0xF70);
        }
        // Fence: the ds_reads below must not be scheduled above the waitcnt.
        __builtin_amdgcn_sched_barrier(0);

        float4 a = st[k % 3][0][wave][lane];
        float4 b = st[k % 3][1][wave][lane];
        float dx = a.x - b.x; acc0 += dx * dx;
        float dy = a.y - b.y; acc1 += dy * dy;
        float dz = a.z - b.z; acc2 += dz * dz;
        float dw = a.w - b.w; acc3 += dw * dw;
    }
    float acc = (acc0 + acc1) + (acc2 + acc3);

    // wave-64 reduce
    #pragma unroll
    for (int off = 32; off > 0; off >>= 1)
        acc += __shfl_down(acc, off, 64);

    __shared__ float wave_sums[4];
    if (lane == 0) wave_sums[wave] = acc;
    __syncthreads();

    if (tid == 0)
        ws[blockIdx.x] = (wave_sums[0] + wave_sums[1]) + (wave_sums[2] + wave_sums[3]);
}

// Kernel 2: reduce 2047 partials -> out[0] = sum * scale.
// Single block of 256; every ws slot read was written by kernel 1.
// Deterministic read order => bit-exact across runs.
__global__ __launch_bounds__(256) void ssd_finalize(const float* __restrict__ ws,
                                                    float* __restrict__ out,
                                                    float scale) {
    const int tid = threadIdx.x;
    float acc = 0.f;
    #pragma unroll
    for (int k = 0; k < 8; ++k) {
        int idx = tid + k * 256;
        if (idx < 2047) acc += ws[idx];
    }

    #pragma unroll
    for (int off = 32; off > 0; off >>= 1)
        acc += __shfl_down(acc, off, 64);

    __shared__ float wave_sums[4];
    const int lane = tid & 63;
    const int wave = tid >> 6;
    if (lane == 0) wave_sums[wave] = acc;
    __syncthreads();

    if (tid == 0)
        out[0] = ((wave_sums[0] + wave_sums[1]) + (wave_sums[2] + wave_sums[3])) * scale;
}

extern "C" void kernel_launch(void* const* d_in, const int* in_sizes, int n_in,
                              void* d_out, int out_size, void* d_ws, size_t ws_size,
                              hipStream_t stream) {
    const float* pred = (const float*)d_in[0];
    const float* targ = (const float*)d_in[1];
    float* out = (float*)d_out;
    float* ws = (float*)d_ws;  // needs 2047 floats = 8188 B

    const int B = 4096;
    const int S = 2047;  // 2*d+1 with d=1023 — slice covers the whole tensor
    const float scale = 1.0f / ((float)S * (float)B);
    // total float4 pairs = B*S*2/4 = 4,192,256 = 2047*256*8 exactly.

    ssd_partials<<<2047, 256, 0, stream>>>((const float4*)pred,
                                           (const float4*)targ, ws);
    ssd_finalize<<<1, 256, 0, stream>>>(ws, out, scale);
}